// Round 6
// baseline (785.832 us; speedup 1.0000x reference)
//
#include <hip/hip_runtime.h>
#include <hip/hip_bf16.h>

// ---------------------------------------------------------------------------
// MwAN forward, MI355X. B=8, QL=128, PL=256, AL=10, E=128, EMB=256.
// Inputs fp32; internal compute fp32 in d_ws; output fp32.
// R16: R15's pin failed because the register ALLOCATOR's budget stayed ~68
//      VGPRs (occupancy heuristic) -> pinned weights were spilled to scratch
//      and re-fetched via VMEM every step (196KB/CU/step through L1 ~= the
//      1690cyc step time; VALUBusy shows no accvgpr/VALU reloads).
//      Fix: amdgpu_waves_per_eu(1,2) on the GRU kernels raises the VGPR
//      budget to 256+ (we only ever run 1 block/CU = 2 waves/EU), so the
//      96-float weight cache stays register-resident. Keep the asm pin.
//      Also: pre prefetch deepened to 2 steps ahead (scalar rotation,
//      order-exact) so HBM latency doesn't bind when the step shrinks.
//      Everything else R14-exact (777.7 us passing baseline).
// ---------------------------------------------------------------------------

#define BB 8
#define QL 128
#define PL 256
#define AL 10
#define EE 128
#define EMB 256
#define G3 384   // 3*H gates
#define HH 128   // hidden

// ---- ws layout (in floats) ----
#define O_XPASS   ((size_t)0)        // (8,256,256)  -- dead after pre-GEMMs; reused
#define O_XQUERY  ((size_t)524288)   // (8,128,256)  -- dead after pre-GEMMs; reused
#define O_XCAND   ((size_t)786432)   // 3 x (8,10,256), chunk 20480
#define O_PREQ    ((size_t)847872)   // (2,8,256,384) -- dead after gru_fwd; reused
#define O_PREP    ((size_t)2420736)  // (2,8,128,384) -- dead after gru_fwd; reused
#define O_PREA    ((size_t)3207168)  // 3 x (2,8,10,384), chunk 61440
#define O_PREG    ((size_t)3391488)  // (2,8,128,384)
#define O_HQ      ((size_t)4177920)  // (8,256,256)
#define O_HP      ((size_t)4702208)  // (8,128,256)
#define O_HCAND   ((size_t)4964352)  // 3 x (8,10,256), chunk 20480
#define O_AEMB    ((size_t)5025792)  // (8,3,256)
#define O_AQ      ((size_t)5031936)  // (8,256,128)
#define O_AP      ((size_t)5294080)  // (8,128,128)
#define O_BQ      ((size_t)5425152)  // (8,256,256)
#define O_AGG     ((size_t)5949440)  // (8,128,1536)
#define O_AGGREP  ((size_t)7522304)  // (8,128,256)
#define O_CQ      ((size_t)7784448)  // (8,256,128)
#define O_GP      ((size_t)8046592)  // (8,128,128)
#define O_RQ      ((size_t)8177664)  // (8,256)
#define O_RQW     ((size_t)8179712)  // (8,128)
#define O_RP      ((size_t)8180736)  // (8,256)
// score / projection staging in DEAD regions (no aliasing between consumers):
#define O_SCD0    O_XPASS                     // dot scores half 0 (8,128,256)
#define O_SCD1    (O_XPASS + (size_t)262144)  // dot scores half 1
#define O_MQ2     O_PREQ                      // Mq = hq@Wm^T (8,256,128)
#define O_MP2     (O_PREQ + (size_t)262144)   // Mp = hp@Wm^T (8,128,128)
#define O_SCS0    O_PREP                      // self scores half 0 (8,128,128)
#define O_SCS1    (O_PREP + (size_t)131072)   // self scores half 1

typedef __attribute__((ext_vector_type(8))) short bf16x8;
typedef __attribute__((ext_vector_type(4))) float f32x4;
typedef __attribute__((ext_vector_type(2))) float v2f;
union U4 { uint4 u; bf16x8 v; };

// barrier with LDS-visibility only
#define BAR_LDS() asm volatile("s_waitcnt lgkmcnt(0)\n\ts_barrier" ::: "memory")

// x += xor1(x); x += xor2(x) via DPP quad_perm (VALU, not DS pipe)
__device__ __forceinline__ float dpp_xadd12(float x){
    int a = __builtin_amdgcn_update_dpp(0, __float_as_int(x), 0xB1, 0xF, 0xF, true); // [1,0,3,2]
    x += __int_as_float(a);
    int b = __builtin_amdgcn_update_dpp(0, __float_as_int(x), 0x4E, 0xF, 0xF, true); // [2,3,0,1]
    x += __int_as_float(b);
    return x;
}

__device__ __forceinline__ float tanh_fast(float x){
    x = fminf(fmaxf(x, -20.f), 20.f);
    float e = __expf(2.f * x);
    return (e - 1.f) / (e + 1.f);
}
__device__ __forceinline__ float sig_fast(float x){
    return 1.f / (1.f + __expf(-x));
}
// pack two fp32 -> bf16 pair (round-half-up)
__device__ __forceinline__ unsigned pk2(float a, float b){
    unsigned ua = __float_as_uint(a), ub = __float_as_uint(b);
    return ((ua + 0x8000u) >> 16) | ((ub + 0x8000u) & 0xffff0000u);
}

// softmax over sc[0..255], 256 lanes (LDS-tree version)
__device__ __forceinline__ void softmax256(float* sc, float* red, int tid){
    float v = sc[tid];
    red[tid] = v;
    __syncthreads();
    for (int s = 128; s > 0; s >>= 1){
        if (tid < s) red[tid] = fmaxf(red[tid], red[tid + s]);
        __syncthreads();
    }
    float m = red[0];
    __syncthreads();
    float e = __expf(v - m);
    red[tid] = e;
    __syncthreads();
    for (int s = 128; s > 0; s >>= 1){
        if (tid < s) red[tid] += red[tid + s];
        __syncthreads();
    }
    float inv = 1.f / red[0];
    __syncthreads();
    sc[tid] = e * inv;
    __syncthreads();
}

// ---------------------------------------------------------------------------
// fused embedding gathers
__global__ __launch_bounds__(256) void k_gather_all(const int* __restrict__ passage,
                                                    const int* __restrict__ query,
                                                    const int* __restrict__ cneg,
                                                    const int* __restrict__ cpos,
                                                    const int* __restrict__ cna,
                                                    const float* __restrict__ emb,
                                                    float* __restrict__ ws){
    int blk = blockIdx.x, e = threadIdx.x;
    const int* ids; size_t dst; int i;
    if (blk < 2048){            ids = passage; dst = O_XPASS;            i = blk; }
    else if (blk < 3072){       ids = query;   dst = O_XQUERY;           i = blk - 2048; }
    else if (blk < 3152){       ids = cneg;    dst = O_XCAND + 0*20480;  i = blk - 3072; }
    else if (blk < 3232){       ids = cpos;    dst = O_XCAND + 1*20480;  i = blk - 3152; }
    else {                      ids = cna;     dst = O_XCAND + 2*20480;  i = blk - 3232; }
    int id = ids[i];
    ws[dst + (size_t)i * EMB + e] = emb[(size_t)id * EMB + e];
}

// ---------------------------------------------------------------------------
// Register-tiled GEMM-NT core (R9 arithmetic, shared mem passed in)
__device__ __forceinline__ void gemm_core(const float* __restrict__ A,
                                          const float* __restrict__ Bm,
                                          const float* __restrict__ bias,
                                          float* __restrict__ C,
                                          int M, int N, int K, int m0, int n0,
                                          float (* __restrict__ As)[68],
                                          float (* __restrict__ Bs)[68]){
    int tid = threadIdx.x;
    int i = tid & 15;
    int j = tid >> 4;
    int sm = tid & 63;
    int sk = (tid >> 6) * 8;

    float acc[4][4];
    #pragma unroll
    for (int r = 0; r < 4; ++r)
        #pragma unroll
        for (int c = 0; c < 4; ++c) acc[r][c] = 0.f;

    for (int k0 = 0; k0 < K; k0 += 32){
        float4 a0 = make_float4(0,0,0,0), a1 = make_float4(0,0,0,0);
        if (m0 + sm < M){
            const float* ap = A + (size_t)(m0 + sm) * K + k0 + sk;
            a0 = *(const float4*)ap;
            a1 = *(const float4*)(ap + 4);
        }
        As[sk+0][sm] = a0.x; As[sk+1][sm] = a0.y; As[sk+2][sm] = a0.z; As[sk+3][sm] = a0.w;
        As[sk+4][sm] = a1.x; As[sk+5][sm] = a1.y; As[sk+6][sm] = a1.z; As[sk+7][sm] = a1.w;
        {
            const float* bp = Bm + (size_t)(n0 + sm) * K + k0 + sk;
            float4 b0 = *(const float4*)bp;
            float4 b1 = *(const float4*)(bp + 4);
            Bs[sk+0][sm] = b0.x; Bs[sk+1][sm] = b0.y; Bs[sk+2][sm] = b0.z; Bs[sk+3][sm] = b0.w;
            Bs[sk+4][sm] = b1.x; Bs[sk+5][sm] = b1.y; Bs[sk+6][sm] = b1.z; Bs[sk+7][sm] = b1.w;
        }
        __syncthreads();
        #pragma unroll
        for (int f = 0; f < 32; ++f){
            float4 av = *(const float4*)&As[f][i*4];
            float4 bv = *(const float4*)&Bs[f][j*4];
            float ar[4] = {av.x, av.y, av.z, av.w};
            float bc[4] = {bv.x, bv.y, bv.z, bv.w};
            #pragma unroll
            for (int r = 0; r < 4; ++r)
                #pragma unroll
                for (int c = 0; c < 4; ++c)
                    acc[r][c] += ar[r] * bc[c];
        }
        __syncthreads();
    }

    float4 bv = make_float4(0,0,0,0);
    if (bias) bv = *(const float4*)&bias[n0 + j*4];
    #pragma unroll
    for (int r = 0; r < 4; ++r){
        int row = m0 + i*4 + r;
        if (row < M){
            float4 o;
            o.x = acc[r][0] + bv.x;
            o.y = acc[r][1] + bv.y;
            o.z = acc[r][2] + bv.z;
            o.w = acc[r][3] + bv.w;
            *(float4*)&C[(size_t)row * N + n0 + j*4] = o;
        }
    }
}

// merged input-preactivation GEMMs: q (384 blks) | p (192) | cand (72)
__global__ __launch_bounds__(256) void k_pre_all(float* __restrict__ ws,
        const float* __restrict__ qW, const float* __restrict__ qb,
        const float* __restrict__ pW, const float* __restrict__ pb,
        const float* __restrict__ aW, const float* __restrict__ ab){
    __shared__ float As[32][68];
    __shared__ float Bs[32][68];
    int blk = blockIdx.x;
    if (blk < 384){
        int z = blk & 1, t = blk >> 1;        // 192 tiles = 32 my x 6 nx
        int my = t / 6, nx = t % 6;
        gemm_core(ws+O_XPASS, qW + (size_t)z*98304, qb + z*384,
                  ws+O_PREQ + (size_t)z*786432, 2048, 384, 256, my*64, nx*64, As, Bs);
    } else if (blk < 576){
        int u = blk - 384; int z = u & 1, t = u >> 1;   // 96 tiles = 16 x 6
        int my = t / 6, nx = t % 6;
        gemm_core(ws+O_XQUERY, pW + (size_t)z*98304, pb + z*384,
                  ws+O_PREP + (size_t)z*393216, 1024, 384, 256, my*64, nx*64, As, Bs);
    } else {
        int u = blk - 576;                    // 72 = 6 zz x 2 my x 6 nx
        int nx = u % 6, my = (u/6) & 1, zz = u / 12;
        int cc = zz >> 1, d = zz & 1;
        gemm_core(ws+O_XCAND + (size_t)cc*20480, aW + (size_t)d*98304, ab + d*384,
                  ws+O_PREA + (size_t)cc*61440 + (size_t)d*30720,
                  80, 384, 256, my*64, nx*64, As, Bs);
    }
}

// agg pre-GEMM (single big dispatch, grid (6,16,2))
__global__ __launch_bounds__(256) void k_gemm_agg(const float* __restrict__ A,
                                                  const float* __restrict__ Bm,
                                                  const float* __restrict__ bias,
                                                  float* __restrict__ C){
    __shared__ float As[32][68];
    __shared__ float Bs[32][68];
    int z = blockIdx.z;
    gemm_core(A, Bm + (size_t)z*589824, bias + z*384, C + (size_t)z*393216,
              1024, 384, 1536, blockIdx.y*64, blockIdx.x*64, As, Bs);
}

// ---------------------------------------------------------------------------
// GRU scan body (R12-exact arithmetic: flat 32-dot chains, dpp quad tree
// reduction). 512 thr, thread=(j,quarter), h_s stride 40.
// R16: 2-step-ahead pre prefetch (scalar rotation, order-exact); weight
// cache pinned via asm; callers carry amdgpu_waves_per_eu(1,2) so the
// allocator's VGPR budget fits the 96-float cache without spilling.
#define HSTRIDE 40
__device__ __forceinline__ void gru_body(const float* __restrict__ pre,
                                         const float* __restrict__ Whh,
                                         const float* __restrict__ bhh,
                                         float* __restrict__ out,
                                         int T, int b, int d){
    int tid = threadIdx.x;
    int j = tid >> 2, q = tid & 3;
    int cb = q * 32;

    v2f wr2[16], wz2[16], wn2[16];
    const float* wb = Whh + (size_t)d * G3 * HH;
    {
        const float4* pr4 = (const float4*)(wb + (size_t)j * HH + cb);
        const float4* pz4 = (const float4*)(wb + (size_t)(HH + j) * HH + cb);
        const float4* pn4 = (const float4*)(wb + (size_t)(2*HH + j) * HH + cb);
        #pragma unroll
        for (int kk = 0; kk < 8; ++kk){
            float4 ur = pr4[kk], uz = pz4[kk], un = pn4[kk];
            wr2[2*kk]   = (v2f){ur.x, ur.y}; wr2[2*kk+1] = (v2f){ur.z, ur.w};
            wz2[2*kk]   = (v2f){uz.x, uz.y}; wz2[2*kk+1] = (v2f){uz.z, uz.w};
            wn2[2*kk]   = (v2f){un.x, un.y}; wn2[2*kk+1] = (v2f){un.z, un.w};
        }
    }
    // pin weight cache in VGPRs (values become asm-produced; with the raised
    // waves_per_eu budget they stay register-resident instead of spilling).
    #pragma unroll
    for (int kk = 0; kk < 16; ++kk){
        asm volatile("" : "+v"(wr2[kk]), "+v"(wz2[kk]), "+v"(wn2[kk]));
    }
    const float* bb = bhh + d * G3;
    float br = bb[j], bz = bb[HH + j], bn = bb[2*HH + j];

    __shared__ __align__(16) float h_s[2][4*HSTRIDE];
    if (tid < 4*HSTRIDE) h_s[0][tid] = 0.f;
    float hprev = 0.f;

    const float* ptB = pre + ((size_t)d * BB + b) * (size_t)T * G3;
    float* ob = out + (size_t)b * T * 256 + d * HH;

    int hw = (j >> 5) * HSTRIDE + (j & 31);   // owner write slot

    // 2-deep prefetch pipeline: p*0 = step s (consume), p*1 = step s+1.
    const float* pt0 = ptB + (size_t)(d ? (T-1) : 0) * G3;
    float pr0 = pt0[j], pz0 = pt0[HH + j], pn0 = pt0[2*HH + j];
    float pr1 = 0.f, pz1 = 0.f, pn1 = 0.f;
    if (T > 1){
        const float* pt1 = ptB + (size_t)(d ? (T-2) : 1) * G3;
        pr1 = pt1[j]; pz1 = pt1[HH + j]; pn1 = pt1[2*HH + j];
    }
    BAR_LDS();

    for (int step = 0; step < T; ++step){
        int t = d ? (T-1-step) : step;
        float nr = 0.f, nz = 0.f, nn = 0.f;
        if (step + 2 < T){
            const float* ptn = ptB + (size_t)(d ? (T-3-step) : (step+2)) * G3;
            nr = ptn[j]; nz = ptn[HH + j]; nn = ptn[2*HH + j];
        }
        int rb = step & 1;
        const float4* h4 = (const float4*)&h_s[rb][q * HSTRIDE];
        v2f ar2 = {0.f,0.f}, az2 = {0.f,0.f}, an2 = {0.f,0.f};
        #pragma unroll
        for (int kk = 0; kk < 8; ++kk){
            float4 hv = h4[kk];
            v2f h0 = {hv.x, hv.y}, h1 = {hv.z, hv.w};
            ar2 += wr2[2*kk] * h0; ar2 += wr2[2*kk+1] * h1;
            az2 += wz2[2*kk] * h0; az2 += wz2[2*kk+1] * h1;
            an2 += wn2[2*kk] * h0; an2 += wn2[2*kk+1] * h1;
        }
        float ar = dpp_xadd12(ar2.x + ar2.y);
        float az = dpp_xadd12(az2.x + az2.y);
        float an = dpp_xadd12(an2.x + an2.y);

        float r = sig_fast(pr0 + ar + br);
        float z = sig_fast(pz0 + az + bz);
        float n = tanh_fast(pn0 + r * (an + bn));
        float h = n + z * (hprev - n);
        hprev = h;

        if (q == 0) h_s[1-rb][hw] = h;
        if (q == 1) ob[(size_t)t * 256 + j] = h;
        pr0 = pr1; pz0 = pz1; pn0 = pn1;
        pr1 = nr;  pz1 = nz;  pn1 = nn;
        BAR_LDS();
    }
}

// fused forward scans: blocks 0-15 q (T=256), 16-31 p (T=128), 32-79 cand (T=10)
__global__ __launch_bounds__(512)
__attribute__((amdgpu_waves_per_eu(1, 2)))
void k_gru_fwd(float* __restrict__ ws,
               const float* __restrict__ qW, const float* __restrict__ qB,
               const float* __restrict__ pW, const float* __restrict__ pB,
               const float* __restrict__ aW, const float* __restrict__ aB){
    int blk = blockIdx.x;
    const float *pre, *W, *bb; float* out; int T, bd;
    if (blk < 16){
        pre = ws + O_PREQ; out = ws + O_HQ; W = qW; bb = qB; T = 256; bd = blk;
    } else if (blk < 32){
        pre = ws + O_PREP; out = ws + O_HP; W = pW; bb = pB; T = 128; bd = blk - 16;
    } else {
        int local = blk - 32; int c = local >> 4;
        pre = ws + O_PREA + (size_t)c * 61440; out = ws + O_HCAND + (size_t)c * 20480;
        W = aW; bb = aB; T = 10; bd = local & 15;
    }
    gru_body(pre, W, bb, out, T, bd >> 1, bd & 1);
}

// single scan (aggregation GRU)
__global__ __launch_bounds__(512)
__attribute__((amdgpu_waves_per_eu(1, 2)))
void k_gru_scan(const float* __restrict__ pre,
                const float* __restrict__ Whh,
                const float* __restrict__ bhh,
                float* __restrict__ out, int T){
    int bd = blockIdx.x & 15;
    gru_body(pre, Whh, bhh, out, T, bd >> 1, bd & 1);
}

// ---------------------------------------------------------------------------
// candidate pooling core (exact R12 arithmetic), smem passed in (288 floats)
__device__ __forceinline__ void cand_att_core(const float* __restrict__ h,
                                              const float* __restrict__ a_att,
                                              float* __restrict__ a_emb,
                                              int u, float* sm){
    int c = u / BB, b = u % BB, tid = threadIdx.x;
    float* att = sm;          // 256
    float* sc  = sm + 256;    // AL
    float* sw  = sm + 256 + 16;
    att[tid] = a_att[tid];
    __syncthreads();
    const float* hb = h + (size_t)c * (BB*AL*256) + (size_t)b * (AL*256);
    if (tid < AL){
        float s = 0.f;
        for (int e = 0; e < 256; ++e) s += hb[tid*256 + e] * att[e];
        sc[tid] = s;
    }
    __syncthreads();
    if (tid == 0){
        float m = -1e30f;
        for (int t = 0; t < AL; ++t) m = fmaxf(m, sc[t]);
        float s = 0.f;
        for (int t = 0; t < AL; ++t){ sw[t] = __expf(sc[t] - m); s += sw[t]; }
        float inv = 1.f / s;
        for (int t = 0; t < AL; ++t) sw[t] *= inv;
    }
    __syncthreads();
    float o = 0.f;
    for (int t = 0; t < AL; ++t) o += sw[t] * hb[t*256 + tid];
    a_emb[((size_t)b*3 + c) * 256 + tid] = o;
}

// merged projection GEMMs + cand_att:
// [0,64) Wc1 | [64,96) Wc2 | [96,224) Wb | [224,288) Wq | [288,352) Wm(hq)
// [352,384) Wm(hp) | [384,408) cand_att
__global__ __launch_bounds__(256) void k_proj_all(float* __restrict__ ws,
        const float* __restrict__ Wc1, const float* __restrict__ Wc2,
        const float* __restrict__ Wb_, const float* __restrict__ Wq_,
        const float* __restrict__ Wm_, const float* __restrict__ a_att){
    __shared__ float As[32][68];
    __shared__ float Bs[32][68];
    int blk = blockIdx.x;
    if (blk < 64){
        int my = blk >> 1, nx = blk & 1;
        gemm_core(ws+O_HQ, Wc1, nullptr, ws+O_AQ, 2048,128,256, my*64, nx*64, As, Bs);
    } else if (blk < 96){
        int u = blk-64; int my = u >> 1, nx = u & 1;
        gemm_core(ws+O_HP, Wc2, nullptr, ws+O_AP, 1024,128,256, my*64, nx*64, As, Bs);
    } else if (blk < 224){
        int u = blk-96; int my = u >> 2, nx = u & 3;
        gemm_core(ws+O_HQ, Wb_, nullptr, ws+O_BQ, 2048,256,256, my*64, nx*64, As, Bs);
    } else if (blk < 288){
        int u = blk-224; int my = u >> 1, nx = u & 1;
        gemm_core(ws+O_HQ, Wq_, nullptr, ws+O_CQ, 2048,128,256, my*64, nx*64, As, Bs);
    } else if (blk < 352){
        int u = blk-288; int my = u >> 1, nx = u & 1;
        gemm_core(ws+O_HQ, Wm_, nullptr, ws+O_MQ2, 2048,128,256, my*64, nx*64, As, Bs);
    } else if (blk < 384){
        int u = blk-352; int my = u >> 1, nx = u & 1;
        gemm_core(ws+O_HP, Wm_, nullptr, ws+O_MP2, 1024,128,256, my*64, nx*64, As, Bs);
    } else {
        cand_att_core(ws+O_HCAND, a_att, ws+O_AEMB, blk-384, (float*)As);
    }
}

// final small GEMMs: [0,32) Wp1 (aggrep->GP) | [32,34) Wp2 (rq->rqW)
__global__ __launch_bounds__(256) void k_fin2(float* __restrict__ ws,
                                              const float* __restrict__ Wp1,
                                              const float* __restrict__ Wp2){
    __shared__ float As[32][68];
    __shared__ float Bs[32][68];
    int blk = blockIdx.x;
    if (blk < 32){
        int my = blk >> 1, nx = blk & 1;
        gemm_core(ws+O_AGGREP, Wp1, nullptr, ws+O_GP, 1024,128,256, my*64, nx*64, As, Bs);
    } else {
        int nx = blk - 32;
        gemm_core(ws+O_RQ, Wp2, nullptr, ws+O_RQW, 8,128,256, 0, nx*64, As, Bs);
    }
}

// ---------------------------------------------------------------------------
// MFMA dms partial scores over a 64-row e-half (exact R12 arithmetic)
__device__ __forceinline__ void dms_core(const float* __restrict__ kv, int P,
                                         const float* __restrict__ Wmat,
                                         const float* __restrict__ v,
                                         const float* __restrict__ xsrc,
                                         int qPerBlock, float* __restrict__ sc,
                                         int pt, int qc, int b,
                                         unsigned* __restrict__ Hlds,
                                         float* __restrict__ hpq){
    int tid = threadIdx.x;
    int w = tid >> 6, lane = tid & 63, m = lane & 15, quad = lane >> 4;

    {
        const float* hr = kv + ((size_t)b * P + pt * 64 + w * 16 + m) * 256;
        unsigned* dst = &Hlds[(w * 16 + m) * 132];
        #pragma unroll
        for (int k0 = 0; k0 < 8; ++k0){
            const float* p0 = hr + k0 * 32 + quad * 8;
            float4 x0 = *(const float4*)p0;
            float4 x1 = *(const float4*)(p0 + 4);
            uint4 u;
            u.x = pk2(x0.x, x0.y); u.y = pk2(x0.z, x0.w);
            u.z = pk2(x1.x, x1.y); u.w = pk2(x1.z, x1.w);
            *(uint4*)&dst[k0 * 16 + quad * 4] = u;
        }
    }

    bf16x8 bfr[4][8];
    #pragma unroll
    for (int et = 0; et < 4; ++et){
        const float* wr = Wmat + (size_t)(et * 16 + m) * 256;
        #pragma unroll
        for (int k0 = 0; k0 < 8; ++k0){
            const float* p0 = wr + k0 * 32 + quad * 8;
            float4 x0 = *(const float4*)p0;
            float4 x1 = *(const float4*)(p0 + 4);
            U4 uu;
            uu.u.x = pk2(x0.x, x0.y); uu.u.y = pk2(x0.z, x0.w);
            uu.u.z = pk2(x1.x, x1.y); uu.u.w = pk2(x1.z, x1.w);
            bfr[et][k0] = uu.v;
        }
    }
    float vreg[4];
    #pragma unroll
    for (int et = 0; et < 4; ++et) vreg[et] = v[et * 16 + m];

    __syncthreads();

    const unsigned* hrow = &Hlds[(w * 16 + m) * 132];

    for (int qi = 0; qi < qPerBlock; ++qi){
        int q = qc * qPerBlock + qi;
        __syncthreads();
        hpq[tid] = xsrc[((size_t)b * QL + q) * 256 + tid];
        __syncthreads();

        bf16x8 afr[8];
        #pragma unroll
        for (int k0 = 0; k0 < 8; ++k0){
            uint4 hv = *(const uint4*)&hrow[k0 * 16 + quad * 4];
            const float* hf = &hpq[k0 * 32 + quad * 8];
            float f0 = __uint_as_float(hv.x << 16)         * hf[0];
            float f1 = __uint_as_float(hv.x & 0xffff0000u) * hf[1];
            float f2 = __uint_as_float(hv.y << 16)         * hf[2];
            float f3 = __uint_as_float(hv.y & 0xffff0000u) * hf[3];
            float f4 = __uint_as_float(hv.z << 16)         * hf[4];
            float f5 = __uint_as_float(hv.z & 0xffff0000u) * hf[5];
            float f6 = __uint_as_float(hv.w << 16)         * hf[6];
            float f7 = __uint_as_float(hv.w & 0xffff0000u) * hf[7];
            U4 uu;
            uu.u.x = pk2(f0, f1); uu.u.y = pk2(f2, f3);
            uu.u.z = pk2(f4, f5); uu.u.w = pk2(f6, f7);
            afr[k0] = uu.v;
        }

        f32x4 acc[4];
        #pragma unroll
        for (int et = 0; et < 4; ++et){
            acc[et][0] = 0.f; acc[et][1] = 0.f; acc[et][2] = 0.f; acc[et][3] = 0.f;
        }
        #pragma unroll
        for (int k0 = 0; k0 < 8; ++k0)
            #pragma unroll
            for (int et = 0; et < 4; ++et)
                acc[et] = __builtin_amdgcn_mfma_f32_16x16x32_bf16(afr[k0], bfr[et][k0], acc[et], 0, 0, 0);

        float p0 = 0.f, p1 = 0.f, p2 = 0.f, p3 = 0.f;
        #pragma unroll
        for (int et = 0; et < 4; ++et){
            p0 += vreg[et] * tanh_fast(acc[et][0]);
            p1 += vreg[et] * tanh_fast(acc[et][1]);
            p2 += vreg[et] * tanh_fast(acc[et][2]);
            p3 += vreg[et] * tanh_fast(acc[et][3]);
        }
        p0 = dpp_xadd12(p0); p0 += __shfl_xor(p0, 4); p0 += __shfl_xor(p0, 8);
        p1 = dpp_xadd12(p1); p1 += __shfl_xor(p1, 4); p1 += __shfl_xor(p1, 8);
        p2 = dpp_xadd12(p2); p2 += __shfl_xor(p2, 4); p2 += __shfl_xor(p2, 8);
        p3 = dpp_xadd12(p3); p3 += __shfl_xor(p3, 4); p3 += __shfl_xor(p3, 8);
        if (m == 0){
            float4 o = make_float4(p0, p1, p2, p3);
            *(float4*)&sc[((size_t)b * QL + q) * P + pt * 64 + w * 16 + quad * 4] = o;
        }
    }
}

// merged dms dispatches:
// [0,256) dot h0 | [256,512) dot h1 | [512,768) self h0 | [768,1024) self h1
__global__ __launch_bounds__(256, 1) void k_dms_all(float* __restrict__ ws,
        const float* __restrict__ Wd, const float* __restrict__ vd,
        const float* __restrict__ Ws_, const float* __restrict__ vs_){
    __shared__ unsigned Hlds[64 * 132];
    __shared__ float hpq[256];
    int blk = blockIdx.x;
    if (blk < 512){
        int h = blk >> 8, u = blk & 255;
        int pt = u & 3, qc = (u >> 2) & 7, b = u >> 5;
        dms_core(ws+O_HQ, 256, Wd + h*16384, vd + h*64, ws+O_HP, 16,
                 ws + (h ? O_SCD1 : O_SCD0), pt, qc, b, Hlds, hpq);
    } else {
        int v2 = blk - 512;
        int h = v2 >> 8, u = v2 & 255;
        int pt = u & 1, qc = (u >> 1) & 15, b = u >> 5;
        dms_core(ws+O_HP, 128, Ws_ + h*16384, vs_ + h*64, ws+O_HP, 8,
                 ws + (h ? O_SCS1 : O_SCS0), pt, qc, b, Hlds, hpq);
    }
}

// ---------------------------------------------------------------------------
// q_att core (exact R12 arithmetic), shares att_fused's smem
__device__ __forceinline__ void q_att_core(const float* __restrict__ Cq,
                                           const float* __restrict__ vq,
                                           const float* __restrict__ hq,
                                           float* __restrict__ rq,
                                           int b, float* vv, float* sc, float* red){
    int tid = threadIdx.x;
    if (tid < EE) vv[tid] = vq[tid];
    __syncthreads();
    const float4* c4 = (const float4*)(Cq + ((size_t)b*PL + tid)*EE);
    float s = 0.f;
    #pragma unroll 4
    for (int e4 = 0; e4 < EE/4; ++e4){
        float4 a = c4[e4];
        int e = e4*4;
        s += vv[e+0]*tanh_fast(a.x); s += vv[e+1]*tanh_fast(a.y);
        s += vv[e+2]*tanh_fast(a.z); s += vv[e+3]*tanh_fast(a.w);
    }
    sc[tid] = s;
    __syncthreads();
    softmax256(sc, red, tid);
    float o = 0.f;
    const float* hqb = hq + (size_t)b*PL*256;
    for (int p = 0; p < PL; ++p) o += sc[p] * hqb[(size_t)p*256 + tid];
    rq[(size_t)b*256 + tid] = o;
}

// ---------------------------------------------------------------------------
// Fused attention: blocks [0,1024): per (b,q) all five context vectors + hp
// copy (XCD-swizzled: b=blk&7); blocks [1024,1032): q_att (b = blk-1024).
__global__ __launch_bounds__(256) void k_att_fused(const float* __restrict__ Aqc,
                                                   const float* __restrict__ Apc,
                                                   const float* __restrict__ vc,
                                                   const float* __restrict__ Mq,
                                                   const float* __restrict__ Mp,
                                                   const float* __restrict__ vm,
                                                   const float* __restrict__ Bq,
                                                   const float* __restrict__ scd0,
                                                   const float* __restrict__ scd1,
                                                   const float* __restrict__ scs0,
                                                   const float* __restrict__ scs1,
                                                   const float* __restrict__ hq,
                                                   const float* __restrict__ hp,
                                                   float* __restrict__ agg,
                                                   const float* __restrict__ Cq,
                                                   const float* __restrict__ vq,
                                                   float* __restrict__ rq){
    __shared__ float apc[EE], apm[EE], vcs[EE], vms[EE], hpr[256];
    __shared__ float wc[256], wm[256], wbv[256], wd[256], wsx[256];
    __shared__ float sred[2][4][5];

    if (blockIdx.x >= 1024){
        q_att_core(Cq, vq, hq, rq, blockIdx.x - 1024, apc, wc, wm);
        return;
    }

    int b = blockIdx.x & 7, q = blockIdx.x >> 3, tid = threadIdx.x;

    if (tid < EE){
        apc[tid] = Apc[((size_t)b*QL + q)*EE + tid];
        apm[tid] = Mp [((size_t)b*QL + q)*EE + tid];
        vcs[tid] = vc[tid];
        vms[tid] = vm[tid];
    }
    float hv = hp[((size_t)b*QL + q)*256 + tid];
    hpr[tid] = hv;
    agg[((size_t)b*QL + q)*1536 + tid] = hv;   // fused hp copy
    __syncthreads();

    // ---- scores (thread = key index p) ----
    int p = tid;
    {   // c: additive tanh
        const float4* a4 = (const float4*)(Aqc + ((size_t)b*PL + p)*EE);
        float s = 0.f;
        #pragma unroll 4
        for (int e4 = 0; e4 < EE/4; ++e4){
            float4 a = a4[e4];
            int e = e4*4;
            s += vcs[e+0] * tanh_fast(a.x + apc[e+0]);
            s += vcs[e+1] * tanh_fast(a.y + apc[e+1]);
            s += vcs[e+2] * tanh_fast(a.z + apc[e+2]);
            s += vcs[e+3] * tanh_fast(a.w + apc[e+3]);
        }
        wc[tid] = s;
    }
    {   // m: subtractive tanh
        const float4* a4 = (const float4*)(Mq + ((size_t)b*PL + p)*EE);
        float s = 0.f;
        #pragma unroll 4
        for (int e4 = 0; e4 < EE/4; ++e4){
            float4 a = a4[e4];
            int e = e4*4;
            s += vms[e+0] * tanh_fast(a.x - apm[e+0]);
            s += vms[e+1] * tanh_fast(a.y - apm[e+1]);
            s += vms[e+2] * tanh_fast(a.z - apm[e+2]);
            s += vms[e+3] * tanh_fast(a.w - apm[e+3]);
        }
        wm[tid] = s;
    }
    {   // b: bilinear dot over 256
        const float4* b4 = (const float4*)(Bq + ((size_t)b*PL + p)*256);
        float s = 0.f;
        #pragma unroll 4
        for (int e4 = 0; e4 < 64; ++e4){
            float4 v = b4[e4];
            int e = e4*4;
            s += hpr[e+0]*v.x; s += hpr[e+1]*v.y;
            s += hpr[e+2]*v.z; s += hpr[e+3]*v.w;
        }
        wbv[tid] = s;
    }
    {   // d: summed halves
        size_t si = ((size_t)b*QL + q)*PL + tid;
        wd[tid] = scd0[si] + scd1[si];
    }
    {   // s: summed halves, 128 keys
        if (tid < QL){
            size_t si = ((size_t)b*QL + q)*QL + tid;
            wsx[tid] = scs0[si] + scs1[si];
        } else {
            wsx[tid] = -1e30f;
        }
    }
    __syncthreads();

    // ---- batched 5-way softmax (wave shuffle + tiny LDS cross-wave) ----
    {
        int wid = tid >> 6, lane = tid & 63;
        float sv[5] = {wc[tid], wm[tid], wbv[tid], wd[tid], wsx[tid]};
        float mx[5], ex[5];
        #pragma unroll
        for (int i = 0; i < 5; ++i){
            float m = sv[i];
            #pragma unroll
            for (int k = 32; k >= 1; k >>= 1) m = fmaxf(m, __shfl_xor(m, k));
            mx[i] = m;
        }
        if (lane == 0){
            #pragma unroll
            for (int i = 0; i < 5; ++i) sred[0][wid][i] = mx[i];
        }
        __syncthreads();
        #pragma unroll
        for (int i = 0; i < 5; ++i){
            float m = fmaxf(fmaxf(sred[0][0][i], sred[0][1][i]),
                            fmaxf(sred[0][2][i], sred[0][3][i]));
            ex[i] = __expf(sv[i] - m);
            float s = ex[i];
            #pragma unroll
            for (int k = 32; k >= 1; k >>= 1) s += __shfl_xor(s, k);
            mx[i] = s;
        }
        if (lane == 0){
            #pragma unroll
            for (int i = 0; i < 5; ++i) sred[1][wid][i] = mx[i];
        }
        __syncthreads();
        #pragma unroll
        for (int i = 0; i < 5; ++i){
            float s = sred[1][0][i] + sred[1][1][i] + sred[1][2][i] + sred[1][3][i];
            ex[i] *= (1.f / s);
        }
        wc[tid] = ex[0]; wm[tid] = ex[1]; wbv[tid] = ex[2]; wd[tid] = ex[3]; wsx[tid] = ex[4];
        __syncthreads();
    }

    // ---- one weighted-sum pass over hq (4 outputs) ----
    float oc = 0.f, om = 0.f, ob = 0.f, od = 0.f;
    const float* hqb = hq + (size_t)b*PL*256;
    #pragma unroll 4
    for (int pp = 0; pp < PL; ++pp){
        float v = hqb[(size_t)pp*256 + tid];
        oc += wc[pp]  * v;
        om += wm[pp]  * v;
        ob += wbv[pp] * v;
        od += wd[pp]  * v;
    }
    // ---- one pass over hp (qts) ----
    float os = 0.f;
    const float* hpb = hp + (size_t)b*QL*256;
    #pragma unroll 4
    for (int k = 0; k < QL; ++k) os += wsx[k] * hpb[(size_t)k*256 + tid];

    float* ag = agg + ((size_t)b*QL + q)*1536;
    ag[ 256 + tid] = os;
    ag[ 512 + tid] = oc;
    ag[ 768 + tid] = od;
    ag[1024 + tid] = ob;
    ag[1280 + tid] = om;
}

// ---------------------------------------------------------------------------
__global__ __launch_bounds__(256) void k_p_att(const float* __restrict__ Gp,
                                               const float* __restrict__ vp,
                                               const float* __restrict__ rqW,
                                               const float* __restrict__ agg_rep,
                                               float* __restrict__ rp){
    int b = blockIdx.x, tid = threadIdx.x;
    __shared__ float vv[EE], rw[EE], sc[256], red[256];
    if (tid < EE){
        vv[tid] = vp[tid];
        rw[tid] = rqW[(size_t)b*EE + tid];
    }
    if (tid >= 128) sc[tid] = -1e30f;
    __syncthreads();
    if (tid < QL){
        const float* gp = Gp + ((size_t)b*QL + tid)*EE;
        float s = 0.f;
        for (int e = 0; e < EE; ++e) s += vv[e] * (gp[e] + rw[e]);
        sc[tid] = s;
    }
    __syncthreads();
    softmax256(sc, red, tid);
    float o = 0.f;
    const float* ab = agg_rep + (size_t)b*QL*256;
    for (int q = 0; q < QL; ++q) o += sc[q] * ab[(size_t)q*256 + tid];
    rp[(size_t)b*256 + tid] = o;
}

__global__ __launch_bounds__(256) void k_final(const float* __restrict__ rp,
                                               const float* __restrict__ Wpred,
                                               const float* __restrict__ a_emb,
                                               float* __restrict__ out){
    int b = blockIdx.x, tid = threadIdx.x;
    __shared__ float rpv[256], enc[256];
    rpv[tid] = rp[(size_t)b*256 + tid];
    __syncthreads();
    const float* wr = Wpred + (size_t)tid*256;
    float s = 0.f;
    #pragma unroll 4
    for (int e = 0; e < 256; ++e) s += wr[e] * rpv[e];
    enc[tid] = (s > 0.f) ? s : 0.01f * s;
    __syncthreads();
    if (tid < 3){
        const float* ae = a_emb + ((size_t)b*3 + tid)*256;
        float o = 0.f;
        for (int e = 0; e < 256; ++e) o += ae[e] * enc[e];
        out[b*3 + tid] = o;
    }
}

// ---------------------------------------------------------------------------
extern "C" void kernel_launch(void* const* d_in, const int* in_sizes, int n_in,
                              void* d_out, int out_size, void* d_ws, size_t ws_size,
                              hipStream_t stream){
    const float* emb   = (const float*)d_in[0];
    const float* a_att = (const float*)d_in[1];
    const float* Wc1   = (const float*)d_in[2];
    const float* Wc2   = (const float*)d_in[3];
    const float* vc    = (const float*)d_in[4];
    const float* Wb    = (const float*)d_in[5];
    const float* Wd    = (const float*)d_in[6];
    const float* vd    = (const float*)d_in[7];
    const float* Wm    = (const float*)d_in[8];
    const float* vm    = (const float*)d_in[9];
    const float* Ws    = (const float*)d_in[10];
    const float* vs    = (const float*)d_in[11];
    const float* Wq    = (const float*)d_in[12];
    const float* vq    = (const float*)d_in[13];
    const float* Wp1   = (const float*)d_in[14];
    const float* Wp2   = (const float*)d_in[15];
    const float* vp    = (const float*)d_in[16];
    const float* Wpred = (const float*)d_in[17];
    const float* q_Wih = (const float*)d_in[18];
    const float* q_Whh = (const float*)d_in[19];
    const float* q_bih = (const float*)d_in[20];
    const float* q_bhh = (const float*)d_in[21];
    const float* p_Wih = (const float*)d_in[22];
    const float* p_Whh = (const float*)d_in[23];
    const float* p_bih = (const float*)d_in[24];
    const float* p_bhh = (const float*)d_in[25];
    const float* a_Wih = (const float*)d_in[26];
    const float* a_Whh = (const float*)d_in[27];
    const float* a_bih = (const float*)d_in[28];
    const float* a_bhh = (const float*)d_in[29];
    const float* g_Wih = (const float*)d_in[30];
    const float* g_Whh = (const float*)d_in[31];
    const float* g_bih = (const float*)d_in[32];
    const float* g_bhh = (const float*)d_in[33];
    const int* query   = (const int*)d_in[34];
    const int* passage = (const int*)d_in[35];
    const int* cneg    = (const int*)d_in[36];
    const int* cpos    = (const int*)d_in[37];
    const int* cna     = (const int*)d_in[38];

    float* ws = (float*)d_ws;

    // 1. embedding gathers
    k_gather_all<<<3312, 256, 0, stream>>>(passage, query, cneg, cpos, cna, emb, ws);

    // 2. input preactivations (q | p | cand merged)
    k_pre_all<<<648, 256, 0, stream>>>(ws, q_Wih, q_bih, p_Wih, p_bih, a_Wih, a_bih);

    // 3. forward GRU scans (q || p || cand in one dispatch)
    k_gru_fwd<<<80, 512, 0, stream>>>(ws, q_Whh, q_bhh, p_Whh, p_bhh, a_Whh, a_bhh);

    // 4. projection GEMMs + cand pooling (merged)
    k_proj_all<<<408, 256, 0, stream>>>(ws, Wc1, Wc2, Wb, Wq, Wm, a_att);

    // 5. dms score halves (dot + self, merged)
    k_dms_all<<<1024, 256, 0, stream>>>(ws, Wd, vd, Ws, vs);

    // 6. fused attention -> all agg slices (+ q_att blocks)
    k_att_fused<<<1032, 256, 0, stream>>>(ws+O_AQ, ws+O_AP, vc,
                                          ws+O_MQ2, ws+O_MP2, vm,
                                          ws+O_BQ,
                                          ws+O_SCD0, ws+O_SCD1,
                                          ws+O_SCS0, ws+O_SCS1,
                                          ws+O_HQ, ws+O_HP, ws+O_AGG,
                                          ws+O_CQ, vq, ws+O_RQ);

    // 7. aggregation bigru
    k_gemm_agg<<<dim3(6,16,2), 256, 0, stream>>>(ws+O_AGG, g_Wih, g_bih, ws+O_PREG);
    k_gru_scan<<<16, 512, 0, stream>>>(ws+O_PREG, g_Whh, g_bhh, ws+O_AGGREP, 128);

    // 8. pooling + prediction
    k_fin2<<<34, 256, 0, stream>>>(ws, Wp1, Wp2);
    k_p_att<<<8, 256, 0, stream>>>(ws+O_GP, vp, ws+O_RQW, ws+O_AGGREP, ws+O_RP);
    k_final<<<8, 256, 0, stream>>>(ws+O_RP, Wpred, ws+O_AEMB, (float*)d_out);
}

// Round 8
// 775.817 us; speedup vs baseline: 1.0129x; 1.0129x over previous
//
#include <hip/hip_runtime.h>
#include <hip/hip_bf16.h>

// ---------------------------------------------------------------------------
// MwAN forward, MI355X. B=8, QL=128, PL=256, AL=10, E=128, EMB=256.
// Inputs fp32; internal compute fp32 in d_ws; output fp32.
// R18: counter re-analysis (VALUBusy 5.9% chip = ~63% on the 32 active CUs)
//      shows gru steps are VALU-ISSUE-bound at ~266 inst/thread/step: the
//      96-float weight cache lives in AGPRs (unified RF spill; invisible to
//      VGPR_Count=68) and v2f/VOP3P gate math forces ~96 v_accvgpr_read per
//      step (VOP3P can't take AGPR operands). Fix: gate accumulators
//      rewritten as SCALAR fma chains in the exact v2f lane order
//      (bit-identical) -> VOP3 v_fma_f32 CAN take AGPR sources, letting
//      si-fold-operands delete the accvgpr reads. Downside ~0 if fold
//      doesn't fire (96 fma + 96 reads == current issue count).
//      Attrs reverted to R14-exact; everything else R14-exact (777.7 us).
// ---------------------------------------------------------------------------

#define BB 8
#define QL 128
#define PL 256
#define AL 10
#define EE 128
#define EMB 256
#define G3 384   // 3*H gates
#define HH 128   // hidden

// ---- ws layout (in floats) ----
#define O_XPASS   ((size_t)0)        // (8,256,256)  -- dead after pre-GEMMs; reused
#define O_XQUERY  ((size_t)524288)   // (8,128,256)  -- dead after pre-GEMMs; reused
#define O_XCAND   ((size_t)786432)   // 3 x (8,10,256), chunk 20480
#define O_PREQ    ((size_t)847872)   // (2,8,256,384) -- dead after gru_fwd; reused
#define O_PREP    ((size_t)2420736)  // (2,8,128,384) -- dead after gru_fwd; reused
#define O_PREA    ((size_t)3207168)  // 3 x (2,8,10,384), chunk 61440
#define O_PREG    ((size_t)3391488)  // (2,8,128,384)
#define O_HQ      ((size_t)4177920)  // (8,256,256)
#define O_HP      ((size_t)4702208)  // (8,128,256)
#define O_HCAND   ((size_t)4964352)  // 3 x (8,10,256), chunk 20480
#define O_AEMB    ((size_t)5025792)  // (8,3,256)
#define O_AQ      ((size_t)5031936)  // (8,256,128)
#define O_AP      ((size_t)5294080)  // (8,128,128)
#define O_BQ      ((size_t)5425152)  // (8,256,256)
#define O_AGG     ((size_t)5949440)  // (8,128,1536)
#define O_AGGREP  ((size_t)7522304)  // (8,128,256)
#define O_CQ      ((size_t)7784448)  // (8,256,128)
#define O_GP      ((size_t)8046592)  // (8,128,128)
#define O_RQ      ((size_t)8177664)  // (8,256)
#define O_RQW     ((size_t)8179712)  // (8,128)
#define O_RP      ((size_t)8180736)  // (8,256)
// score / projection staging in DEAD regions (no aliasing between consumers):
#define O_SCD0    O_XPASS                     // dot scores half 0 (8,128,256)
#define O_SCD1    (O_XPASS + (size_t)262144)  // dot scores half 1
#define O_MQ2     O_PREQ                      // Mq = hq@Wm^T (8,256,128)
#define O_MP2     (O_PREQ + (size_t)262144)   // Mp = hp@Wm^T (8,128,128)
#define O_SCS0    O_PREP                      // self scores half 0 (8,128,128)
#define O_SCS1    (O_PREP + (size_t)131072)   // self scores half 1

typedef __attribute__((ext_vector_type(8))) short bf16x8;
typedef __attribute__((ext_vector_type(4))) float f32x4;
typedef __attribute__((ext_vector_type(2))) float v2f;
union U4 { uint4 u; bf16x8 v; };

// barrier with LDS-visibility only
#define BAR_LDS() asm volatile("s_waitcnt lgkmcnt(0)\n\ts_barrier" ::: "memory")

// x += xor1(x); x += xor2(x) via DPP quad_perm (VALU, not DS pipe)
__device__ __forceinline__ float dpp_xadd12(float x){
    int a = __builtin_amdgcn_update_dpp(0, __float_as_int(x), 0xB1, 0xF, 0xF, true); // [1,0,3,2]
    x += __int_as_float(a);
    int b = __builtin_amdgcn_update_dpp(0, __float_as_int(x), 0x4E, 0xF, 0xF, true); // [2,3,0,1]
    x += __int_as_float(b);
    return x;
}

__device__ __forceinline__ float tanh_fast(float x){
    x = fminf(fmaxf(x, -20.f), 20.f);
    float e = __expf(2.f * x);
    return (e - 1.f) / (e + 1.f);
}
__device__ __forceinline__ float sig_fast(float x){
    return 1.f / (1.f + __expf(-x));
}
// pack two fp32 -> bf16 pair (round-half-up)
__device__ __forceinline__ unsigned pk2(float a, float b){
    unsigned ua = __float_as_uint(a), ub = __float_as_uint(b);
    return ((ua + 0x8000u) >> 16) | ((ub + 0x8000u) & 0xffff0000u);
}

// softmax over sc[0..255], 256 lanes (LDS-tree version)
__device__ __forceinline__ void softmax256(float* sc, float* red, int tid){
    float v = sc[tid];
    red[tid] = v;
    __syncthreads();
    for (int s = 128; s > 0; s >>= 1){
        if (tid < s) red[tid] = fmaxf(red[tid], red[tid + s]);
        __syncthreads();
    }
    float m = red[0];
    __syncthreads();
    float e = __expf(v - m);
    red[tid] = e;
    __syncthreads();
    for (int s = 128; s > 0; s >>= 1){
        if (tid < s) red[tid] += red[tid + s];
        __syncthreads();
    }
    float inv = 1.f / red[0];
    __syncthreads();
    sc[tid] = e * inv;
    __syncthreads();
}

// ---------------------------------------------------------------------------
// fused embedding gathers
__global__ __launch_bounds__(256) void k_gather_all(const int* __restrict__ passage,
                                                    const int* __restrict__ query,
                                                    const int* __restrict__ cneg,
                                                    const int* __restrict__ cpos,
                                                    const int* __restrict__ cna,
                                                    const float* __restrict__ emb,
                                                    float* __restrict__ ws){
    int blk = blockIdx.x, e = threadIdx.x;
    const int* ids; size_t dst; int i;
    if (blk < 2048){            ids = passage; dst = O_XPASS;            i = blk; }
    else if (blk < 3072){       ids = query;   dst = O_XQUERY;           i = blk - 2048; }
    else if (blk < 3152){       ids = cneg;    dst = O_XCAND + 0*20480;  i = blk - 3072; }
    else if (blk < 3232){       ids = cpos;    dst = O_XCAND + 1*20480;  i = blk - 3152; }
    else {                      ids = cna;     dst = O_XCAND + 2*20480;  i = blk - 3232; }
    int id = ids[i];
    ws[dst + (size_t)i * EMB + e] = emb[(size_t)id * EMB + e];
}

// ---------------------------------------------------------------------------
// Register-tiled GEMM-NT core (R9 arithmetic, shared mem passed in)
__device__ __forceinline__ void gemm_core(const float* __restrict__ A,
                                          const float* __restrict__ Bm,
                                          const float* __restrict__ bias,
                                          float* __restrict__ C,
                                          int M, int N, int K, int m0, int n0,
                                          float (* __restrict__ As)[68],
                                          float (* __restrict__ Bs)[68]){
    int tid = threadIdx.x;
    int i = tid & 15;
    int j = tid >> 4;
    int sm = tid & 63;
    int sk = (tid >> 6) * 8;

    float acc[4][4];
    #pragma unroll
    for (int r = 0; r < 4; ++r)
        #pragma unroll
        for (int c = 0; c < 4; ++c) acc[r][c] = 0.f;

    for (int k0 = 0; k0 < K; k0 += 32){
        float4 a0 = make_float4(0,0,0,0), a1 = make_float4(0,0,0,0);
        if (m0 + sm < M){
            const float* ap = A + (size_t)(m0 + sm) * K + k0 + sk;
            a0 = *(const float4*)ap;
            a1 = *(const float4*)(ap + 4);
        }
        As[sk+0][sm] = a0.x; As[sk+1][sm] = a0.y; As[sk+2][sm] = a0.z; As[sk+3][sm] = a0.w;
        As[sk+4][sm] = a1.x; As[sk+5][sm] = a1.y; As[sk+6][sm] = a1.z; As[sk+7][sm] = a1.w;
        {
            const float* bp = Bm + (size_t)(n0 + sm) * K + k0 + sk;
            float4 b0 = *(const float4*)bp;
            float4 b1 = *(const float4*)(bp + 4);
            Bs[sk+0][sm] = b0.x; Bs[sk+1][sm] = b0.y; Bs[sk+2][sm] = b0.z; Bs[sk+3][sm] = b0.w;
            Bs[sk+4][sm] = b1.x; Bs[sk+5][sm] = b1.y; Bs[sk+6][sm] = b1.z; Bs[sk+7][sm] = b1.w;
        }
        __syncthreads();
        #pragma unroll
        for (int f = 0; f < 32; ++f){
            float4 av = *(const float4*)&As[f][i*4];
            float4 bv = *(const float4*)&Bs[f][j*4];
            float ar[4] = {av.x, av.y, av.z, av.w};
            float bc[4] = {bv.x, bv.y, bv.z, bv.w};
            #pragma unroll
            for (int r = 0; r < 4; ++r)
                #pragma unroll
                for (int c = 0; c < 4; ++c)
                    acc[r][c] += ar[r] * bc[c];
        }
        __syncthreads();
    }

    float4 bv = make_float4(0,0,0,0);
    if (bias) bv = *(const float4*)&bias[n0 + j*4];
    #pragma unroll
    for (int r = 0; r < 4; ++r){
        int row = m0 + i*4 + r;
        if (row < M){
            float4 o;
            o.x = acc[r][0] + bv.x;
            o.y = acc[r][1] + bv.y;
            o.z = acc[r][2] + bv.z;
            o.w = acc[r][3] + bv.w;
            *(float4*)&C[(size_t)row * N + n0 + j*4] = o;
        }
    }
}

// merged input-preactivation GEMMs: q (384 blks) | p (192) | cand (72)
__global__ __launch_bounds__(256) void k_pre_all(float* __restrict__ ws,
        const float* __restrict__ qW, const float* __restrict__ qb,
        const float* __restrict__ pW, const float* __restrict__ pb,
        const float* __restrict__ aW, const float* __restrict__ ab){
    __shared__ float As[32][68];
    __shared__ float Bs[32][68];
    int blk = blockIdx.x;
    if (blk < 384){
        int z = blk & 1, t = blk >> 1;        // 192 tiles = 32 my x 6 nx
        int my = t / 6, nx = t % 6;
        gemm_core(ws+O_XPASS, qW + (size_t)z*98304, qb + z*384,
                  ws+O_PREQ + (size_t)z*786432, 2048, 384, 256, my*64, nx*64, As, Bs);
    } else if (blk < 576){
        int u = blk - 384; int z = u & 1, t = u >> 1;   // 96 tiles = 16 x 6
        int my = t / 6, nx = t % 6;
        gemm_core(ws+O_XQUERY, pW + (size_t)z*98304, pb + z*384,
                  ws+O_PREP + (size_t)z*393216, 1024, 384, 256, my*64, nx*64, As, Bs);
    } else {
        int u = blk - 576;                    // 72 = 6 zz x 2 my x 6 nx
        int nx = u % 6, my = (u/6) & 1, zz = u / 12;
        int cc = zz >> 1, d = zz & 1;
        gemm_core(ws+O_XCAND + (size_t)cc*20480, aW + (size_t)d*98304, ab + d*384,
                  ws+O_PREA + (size_t)cc*61440 + (size_t)d*30720,
                  80, 384, 256, my*64, nx*64, As, Bs);
    }
}

// agg pre-GEMM (single big dispatch, grid (6,16,2))
__global__ __launch_bounds__(256) void k_gemm_agg(const float* __restrict__ A,
                                                  const float* __restrict__ Bm,
                                                  const float* __restrict__ bias,
                                                  float* __restrict__ C){
    __shared__ float As[32][68];
    __shared__ float Bs[32][68];
    int z = blockIdx.z;
    gemm_core(A, Bm + (size_t)z*589824, bias + z*384, C + (size_t)z*393216,
              1024, 384, 1536, blockIdx.y*64, blockIdx.x*64, As, Bs);
}

// ---------------------------------------------------------------------------
// GRU scan body. 512 thr, thread=(j,quarter), h_s stride 40, 1 barrier/step,
// 1-step-ahead global prefetch (R14-exact structure).
// R18: gate dot-products as SCALAR fma chains in the exact v2f lane order
// (x-chain = even k, y-chain = odd k, same sequence, fused) -> VOP3
// v_fma_f32 can source AGPR-resident weights directly, eliminating the
// per-step v_accvgpr_read traffic that VOP3P (pk_fma) forces.
#define HSTRIDE 40
__device__ __forceinline__ void gru_body(const float* __restrict__ pre,
                                         const float* __restrict__ Whh,
                                         const float* __restrict__ bhh,
                                         float* __restrict__ out,
                                         int T, int b, int d){
    int tid = threadIdx.x;
    int j = tid >> 2, q = tid & 3;
    int cb = q * 32;

    float wr[32], wz[32], wn[32];
    const float* wb = Whh + (size_t)d * G3 * HH;
    {
        const float4* pr4 = (const float4*)(wb + (size_t)j * HH + cb);
        const float4* pz4 = (const float4*)(wb + (size_t)(HH + j) * HH + cb);
        const float4* pn4 = (const float4*)(wb + (size_t)(2*HH + j) * HH + cb);
        #pragma unroll
        for (int kk = 0; kk < 8; ++kk){
            float4 ur = pr4[kk], uz = pz4[kk], un = pn4[kk];
            wr[4*kk+0] = ur.x; wr[4*kk+1] = ur.y; wr[4*kk+2] = ur.z; wr[4*kk+3] = ur.w;
            wz[4*kk+0] = uz.x; wz[4*kk+1] = uz.y; wz[4*kk+2] = uz.z; wz[4*kk+3] = uz.w;
            wn[4*kk+0] = un.x; wn[4*kk+1] = un.y; wn[4*kk+2] = un.z; wn[4*kk+3] = un.w;
        }
    }
    const float* bb = bhh + d * G3;
    float br = bb[j], bz = bb[HH + j], bn = bb[2*HH + j];

    __shared__ __align__(16) float h_s[2][4*HSTRIDE];
    if (tid < 4*HSTRIDE) h_s[0][tid] = 0.f;
    float hprev = 0.f;

    const float* ptB = pre + ((size_t)d * BB + b) * (size_t)T * G3;
    float* ob = out + (size_t)b * T * 256 + d * HH;

    int hw = (j >> 5) * HSTRIDE + (j & 31);   // owner write slot

    const float* pt0 = ptB + (size_t)(d ? (T-1) : 0) * G3;
    float pr = pt0[j], pz = pt0[HH + j], pn = pt0[2*HH + j];
    BAR_LDS();

    for (int step = 0; step < T; ++step){
        int t = d ? (T-1-step) : step;
        float nr = 0.f, nz = 0.f, nn = 0.f;
        if (step + 1 < T){
            const float* ptn = ptB + (size_t)(d ? (T-2-step) : (step+1)) * G3;
            nr = ptn[j]; nz = ptn[HH + j]; nn = ptn[2*HH + j];
        }
        int rb = step & 1;
        const float4* h4 = (const float4*)&h_s[rb][q * HSTRIDE];
        // scalar chains, exact v2f lane order: x-chain = even k, y-chain = odd k
        float arx = 0.f, ary = 0.f, azx = 0.f, azy = 0.f, anx = 0.f, any_ = 0.f;
        #pragma unroll
        for (int kk = 0; kk < 8; ++kk){
            float4 hv = h4[kk];
            arx += wr[4*kk+0] * hv.x; ary += wr[4*kk+1] * hv.y;
            arx += wr[4*kk+2] * hv.z; ary += wr[4*kk+3] * hv.w;
            azx += wz[4*kk+0] * hv.x; azy += wz[4*kk+1] * hv.y;
            azx += wz[4*kk+2] * hv.z; azy += wz[4*kk+3] * hv.w;
            anx += wn[4*kk+0] * hv.x; any_ += wn[4*kk+1] * hv.y;
            anx += wn[4*kk+2] * hv.z; any_ += wn[4*kk+3] * hv.w;
        }
        float ar = dpp_xadd12(arx + ary);
        float az = dpp_xadd12(azx + azy);
        float an = dpp_xadd12(anx + any_);

        float r = sig_fast(pr + ar + br);
        float z = sig_fast(pz + az + bz);
        float n = tanh_fast(pn + r * (an + bn));
        float h = n + z * (hprev - n);
        hprev = h;

        if (q == 0) h_s[1-rb][hw] = h;
        if (q == 1) ob[(size_t)t * 256 + j] = h;
        pr = nr; pz = nz; pn = nn;
        BAR_LDS();
    }
}

// fused forward scans: blocks 0-15 q (T=256), 16-31 p (T=128), 32-79 cand (T=10)
__global__ __launch_bounds__(512, 1) void k_gru_fwd(float* __restrict__ ws,
                                                    const float* __restrict__ qW, const float* __restrict__ qB,
                                                    const float* __restrict__ pW, const float* __restrict__ pB,
                                                    const float* __restrict__ aW, const float* __restrict__ aB){
    int blk = blockIdx.x;
    const float *pre, *W, *bb; float* out; int T, bd;
    if (blk < 16){
        pre = ws + O_PREQ; out = ws + O_HQ; W = qW; bb = qB; T = 256; bd = blk;
    } else if (blk < 32){
        pre = ws + O_PREP; out = ws + O_HP; W = pW; bb = pB; T = 128; bd = blk - 16;
    } else {
        int local = blk - 32; int c = local >> 4;
        pre = ws + O_PREA + (size_t)c * 61440; out = ws + O_HCAND + (size_t)c * 20480;
        W = aW; bb = aB; T = 10; bd = local & 15;
    }
    gru_body(pre, W, bb, out, T, bd >> 1, bd & 1);
}

// single scan (aggregation GRU)
__global__ __launch_bounds__(512, 1) void k_gru_scan(const float* __restrict__ pre,
                                                     const float* __restrict__ Whh,
                                                     const float* __restrict__ bhh,
                                                     float* __restrict__ out, int T){
    int bd = blockIdx.x & 15;
    gru_body(pre, Whh, bhh, out, T, bd >> 1, bd & 1);
}

// ---------------------------------------------------------------------------
// candidate pooling core (exact R12 arithmetic), smem passed in (288 floats)
__device__ __forceinline__ void cand_att_core(const float* __restrict__ h,
                                              const float* __restrict__ a_att,
                                              float* __restrict__ a_emb,
                                              int u, float* sm){
    int c = u / BB, b = u % BB, tid = threadIdx.x;
    float* att = sm;          // 256
    float* sc  = sm + 256;    // AL
    float* sw  = sm + 256 + 16;
    att[tid] = a_att[tid];
    __syncthreads();
    const float* hb = h + (size_t)c * (BB*AL*256) + (size_t)b * (AL*256);
    if (tid < AL){
        float s = 0.f;
        for (int e = 0; e < 256; ++e) s += hb[tid*256 + e] * att[e];
        sc[tid] = s;
    }
    __syncthreads();
    if (tid == 0){
        float m = -1e30f;
        for (int t = 0; t < AL; ++t) m = fmaxf(m, sc[t]);
        float s = 0.f;
        for (int t = 0; t < AL; ++t){ sw[t] = __expf(sc[t] - m); s += sw[t]; }
        float inv = 1.f / s;
        for (int t = 0; t < AL; ++t) sw[t] *= inv;
    }
    __syncthreads();
    float o = 0.f;
    for (int t = 0; t < AL; ++t) o += sw[t] * hb[t*256 + tid];
    a_emb[((size_t)b*3 + c) * 256 + tid] = o;
}

// merged projection GEMMs + cand_att:
// [0,64) Wc1 | [64,96) Wc2 | [96,224) Wb | [224,288) Wq | [288,352) Wm(hq)
// [352,384) Wm(hp) | [384,408) cand_att
__global__ __launch_bounds__(256) void k_proj_all(float* __restrict__ ws,
        const float* __restrict__ Wc1, const float* __restrict__ Wc2,
        const float* __restrict__ Wb_, const float* __restrict__ Wq_,
        const float* __restrict__ Wm_, const float* __restrict__ a_att){
    __shared__ float As[32][68];
    __shared__ float Bs[32][68];
    int blk = blockIdx.x;
    if (blk < 64){
        int my = blk >> 1, nx = blk & 1;
        gemm_core(ws+O_HQ, Wc1, nullptr, ws+O_AQ, 2048,128,256, my*64, nx*64, As, Bs);
    } else if (blk < 96){
        int u = blk-64; int my = u >> 1, nx = u & 1;
        gemm_core(ws+O_HP, Wc2, nullptr, ws+O_AP, 1024,128,256, my*64, nx*64, As, Bs);
    } else if (blk < 224){
        int u = blk-96; int my = u >> 2, nx = u & 3;
        gemm_core(ws+O_HQ, Wb_, nullptr, ws+O_BQ, 2048,256,256, my*64, nx*64, As, Bs);
    } else if (blk < 288){
        int u = blk-224; int my = u >> 1, nx = u & 1;
        gemm_core(ws+O_HQ, Wq_, nullptr, ws+O_CQ, 2048,128,256, my*64, nx*64, As, Bs);
    } else if (blk < 352){
        int u = blk-288; int my = u >> 1, nx = u & 1;
        gemm_core(ws+O_HQ, Wm_, nullptr, ws+O_MQ2, 2048,128,256, my*64, nx*64, As, Bs);
    } else if (blk < 384){
        int u = blk-352; int my = u >> 1, nx = u & 1;
        gemm_core(ws+O_HP, Wm_, nullptr, ws+O_MP2, 1024,128,256, my*64, nx*64, As, Bs);
    } else {
        cand_att_core(ws+O_HCAND, a_att, ws+O_AEMB, blk-384, (float*)As);
    }
}

// final small GEMMs: [0,32) Wp1 (aggrep->GP) | [32,34) Wp2 (rq->rqW)
__global__ __launch_bounds__(256) void k_fin2(float* __restrict__ ws,
                                              const float* __restrict__ Wp1,
                                              const float* __restrict__ Wp2){
    __shared__ float As[32][68];
    __shared__ float Bs[32][68];
    int blk = blockIdx.x;
    if (blk < 32){
        int my = blk >> 1, nx = blk & 1;
        gemm_core(ws+O_AGGREP, Wp1, nullptr, ws+O_GP, 1024,128,256, my*64, nx*64, As, Bs);
    } else {
        int nx = blk - 32;
        gemm_core(ws+O_RQ, Wp2, nullptr, ws+O_RQW, 8,128,256, 0, nx*64, As, Bs);
    }
}

// ---------------------------------------------------------------------------
// MFMA dms partial scores over a 64-row e-half (exact R12 arithmetic)
__device__ __forceinline__ void dms_core(const float* __restrict__ kv, int P,
                                         const float* __restrict__ Wmat,
                                         const float* __restrict__ v,
                                         const float* __restrict__ xsrc,
                                         int qPerBlock, float* __restrict__ sc,
                                         int pt, int qc, int b,
                                         unsigned* __restrict__ Hlds,
                                         float* __restrict__ hpq){
    int tid = threadIdx.x;
    int w = tid >> 6, lane = tid & 63, m = lane & 15, quad = lane >> 4;

    {
        const float* hr = kv + ((size_t)b * P + pt * 64 + w * 16 + m) * 256;
        unsigned* dst = &Hlds[(w * 16 + m) * 132];
        #pragma unroll
        for (int k0 = 0; k0 < 8; ++k0){
            const float* p0 = hr + k0 * 32 + quad * 8;
            float4 x0 = *(const float4*)p0;
            float4 x1 = *(const float4*)(p0 + 4);
            uint4 u;
            u.x = pk2(x0.x, x0.y); u.y = pk2(x0.z, x0.w);
            u.z = pk2(x1.x, x1.y); u.w = pk2(x1.z, x1.w);
            *(uint4*)&dst[k0 * 16 + quad * 4] = u;
        }
    }

    bf16x8 bfr[4][8];
    #pragma unroll
    for (int et = 0; et < 4; ++et){
        const float* wr = Wmat + (size_t)(et * 16 + m) * 256;
        #pragma unroll
        for (int k0 = 0; k0 < 8; ++k0){
            const float* p0 = wr + k0 * 32 + quad * 8;
            float4 x0 = *(const float4*)p0;
            float4 x1 = *(const float4*)(p0 + 4);
            U4 uu;
            uu.u.x = pk2(x0.x, x0.y); uu.u.y = pk2(x0.z, x0.w);
            uu.u.z = pk2(x1.x, x1.y); uu.u.w = pk2(x1.z, x1.w);
            bfr[et][k0] = uu.v;
        }
    }
    float vreg[4];
    #pragma unroll
    for (int et = 0; et < 4; ++et) vreg[et] = v[et * 16 + m];

    __syncthreads();

    const unsigned* hrow = &Hlds[(w * 16 + m) * 132];

    for (int qi = 0; qi < qPerBlock; ++qi){
        int q = qc * qPerBlock + qi;
        __syncthreads();
        hpq[tid] = xsrc[((size_t)b * QL + q) * 256 + tid];
        __syncthreads();

        bf16x8 afr[8];
        #pragma unroll
        for (int k0 = 0; k0 < 8; ++k0){
            uint4 hv = *(const uint4*)&hrow[k0 * 16 + quad * 4];
            const float* hf = &hpq[k0 * 32 + quad * 8];
            float f0 = __uint_as_float(hv.x << 16)         * hf[0];
            float f1 = __uint_as_float(hv.x & 0xffff0000u) * hf[1];
            float f2 = __uint_as_float(hv.y << 16)         * hf[2];
            float f3 = __uint_as_float(hv.y & 0xffff0000u) * hf[3];
            float f4 = __uint_as_float(hv.z << 16)         * hf[4];
            float f5 = __uint_as_float(hv.z & 0xffff0000u) * hf[5];
            float f6 = __uint_as_float(hv.w << 16)         * hf[6];
            float f7 = __uint_as_float(hv.w & 0xffff0000u) * hf[7];
            U4 uu;
            uu.u.x = pk2(f0, f1); uu.u.y = pk2(f2, f3);
            uu.u.z = pk2(f4, f5); uu.u.w = pk2(f6, f7);
            afr[k0] = uu.v;
        }

        f32x4 acc[4];
        #pragma unroll
        for (int et = 0; et < 4; ++et){
            acc[et][0] = 0.f; acc[et][1] = 0.f; acc[et][2] = 0.f; acc[et][3] = 0.f;
        }
        #pragma unroll
        for (int k0 = 0; k0 < 8; ++k0)
            #pragma unroll
            for (int et = 0; et < 4; ++et)
                acc[et] = __builtin_amdgcn_mfma_f32_16x16x32_bf16(afr[k0], bfr[et][k0], acc[et], 0, 0, 0);

        float p0 = 0.f, p1 = 0.f, p2 = 0.f, p3 = 0.f;
        #pragma unroll
        for (int et = 0; et < 4; ++et){
            p0 += vreg[et] * tanh_fast(acc[et][0]);
            p1 += vreg[et] * tanh_fast(acc[et][1]);
            p2 += vreg[et] * tanh_fast(acc[et][2]);
            p3 += vreg[et] * tanh_fast(acc[et][3]);
        }
        p0 = dpp_xadd12(p0); p0 += __shfl_xor(p0, 4); p0 += __shfl_xor(p0, 8);
        p1 = dpp_xadd12(p1); p1 += __shfl_xor(p1, 4); p1 += __shfl_xor(p1, 8);
        p2 = dpp_xadd12(p2); p2 += __shfl_xor(p2, 4); p2 += __shfl_xor(p2, 8);
        p3 = dpp_xadd12(p3); p3 += __shfl_xor(p3, 4); p3 += __shfl_xor(p3, 8);
        if (m == 0){
            float4 o = make_float4(p0, p1, p2, p3);
            *(float4*)&sc[((size_t)b * QL + q) * P + pt * 64 + w * 16 + quad * 4] = o;
        }
    }
}

// merged dms dispatches:
// [0,256) dot h0 | [256,512) dot h1 | [512,768) self h0 | [768,1024) self h1
__global__ __launch_bounds__(256, 1) void k_dms_all(float* __restrict__ ws,
        const float* __restrict__ Wd, const float* __restrict__ vd,
        const float* __restrict__ Ws_, const float* __restrict__ vs_){
    __shared__ unsigned Hlds[64 * 132];
    __shared__ float hpq[256];
    int blk = blockIdx.x;
    if (blk < 512){
        int h = blk >> 8, u = blk & 255;
        int pt = u & 3, qc = (u >> 2) & 7, b = u >> 5;
        dms_core(ws+O_HQ, 256, Wd + h*16384, vd + h*64, ws+O_HP, 16,
                 ws + (h ? O_SCD1 : O_SCD0), pt, qc, b, Hlds, hpq);
    } else {
        int v2 = blk - 512;
        int h = v2 >> 8, u = v2 & 255;
        int pt = u & 1, qc = (u >> 1) & 15, b = u >> 5;
        dms_core(ws+O_HP, 128, Ws_ + h*16384, vs_ + h*64, ws+O_HP, 8,
                 ws + (h ? O_SCS1 : O_SCS0), pt, qc, b, Hlds, hpq);
    }
}

// ---------------------------------------------------------------------------
// q_att core (exact R12 arithmetic), shares att_fused's smem
__device__ __forceinline__ void q_att_core(const float* __restrict__ Cq,
                                           const float* __restrict__ vq,
                                           const float* __restrict__ hq,
                                           float* __restrict__ rq,
                                           int b, float* vv, float* sc, float* red){
    int tid = threadIdx.x;
    if (tid < EE) vv[tid] = vq[tid];
    __syncthreads();
    const float4* c4 = (const float4*)(Cq + ((size_t)b*PL + tid)*EE);
    float s = 0.f;
    #pragma unroll 4
    for (int e4 = 0; e4 < EE/4; ++e4){
        float4 a = c4[e4];
        int e = e4*4;
        s += vv[e+0]*tanh_fast(a.x); s += vv[e+1]*tanh_fast(a.y);
        s += vv[e+2]*tanh_fast(a.z); s += vv[e+3]*tanh_fast(a.w);
    }
    sc[tid] = s;
    __syncthreads();
    softmax256(sc, red, tid);
    float o = 0.f;
    const float* hqb = hq + (size_t)b*PL*256;
    for (int p = 0; p < PL; ++p) o += sc[p] * hqb[(size_t)p*256 + tid];
    rq[(size_t)b*256 + tid] = o;
}

// ---------------------------------------------------------------------------
// Fused attention: blocks [0,1024): per (b,q) all five context vectors + hp
// copy (XCD-swizzled: b=blk&7); blocks [1024,1032): q_att (b = blk-1024).
__global__ __launch_bounds__(256) void k_att_fused(const float* __restrict__ Aqc,
                                                   const float* __restrict__ Apc,
                                                   const float* __restrict__ vc,
                                                   const float* __restrict__ Mq,
                                                   const float* __restrict__ Mp,
                                                   const float* __restrict__ vm,
                                                   const float* __restrict__ Bq,
                                                   const float* __restrict__ scd0,
                                                   const float* __restrict__ scd1,
                                                   const float* __restrict__ scs0,
                                                   const float* __restrict__ scs1,
                                                   const float* __restrict__ hq,
                                                   const float* __restrict__ hp,
                                                   float* __restrict__ agg,
                                                   const float* __restrict__ Cq,
                                                   const float* __restrict__ vq,
                                                   float* __restrict__ rq){
    __shared__ float apc[EE], apm[EE], vcs[EE], vms[EE], hpr[256];
    __shared__ float wc[256], wm[256], wbv[256], wd[256], wsx[256];
    __shared__ float sred[2][4][5];

    if (blockIdx.x >= 1024){
        q_att_core(Cq, vq, hq, rq, blockIdx.x - 1024, apc, wc, wm);
        return;
    }

    int b = blockIdx.x & 7, q = blockIdx.x >> 3, tid = threadIdx.x;

    if (tid < EE){
        apc[tid] = Apc[((size_t)b*QL + q)*EE + tid];
        apm[tid] = Mp [((size_t)b*QL + q)*EE + tid];
        vcs[tid] = vc[tid];
        vms[tid] = vm[tid];
    }
    float hv = hp[((size_t)b*QL + q)*256 + tid];
    hpr[tid] = hv;
    agg[((size_t)b*QL + q)*1536 + tid] = hv;   // fused hp copy
    __syncthreads();

    // ---- scores (thread = key index p) ----
    int p = tid;
    {   // c: additive tanh
        const float4* a4 = (const float4*)(Aqc + ((size_t)b*PL + p)*EE);
        float s = 0.f;
        #pragma unroll 4
        for (int e4 = 0; e4 < EE/4; ++e4){
            float4 a = a4[e4];
            int e = e4*4;
            s += vcs[e+0] * tanh_fast(a.x + apc[e+0]);
            s += vcs[e+1] * tanh_fast(a.y + apc[e+1]);
            s += vcs[e+2] * tanh_fast(a.z + apc[e+2]);
            s += vcs[e+3] * tanh_fast(a.w + apc[e+3]);
        }
        wc[tid] = s;
    }
    {   // m: subtractive tanh
        const float4* a4 = (const float4*)(Mq + ((size_t)b*PL + p)*EE);
        float s = 0.f;
        #pragma unroll 4
        for (int e4 = 0; e4 < EE/4; ++e4){
            float4 a = a4[e4];
            int e = e4*4;
            s += vms[e+0] * tanh_fast(a.x - apm[e+0]);
            s += vms[e+1] * tanh_fast(a.y - apm[e+1]);
            s += vms[e+2] * tanh_fast(a.z - apm[e+2]);
            s += vms[e+3] * tanh_fast(a.w - apm[e+3]);
        }
        wm[tid] = s;
    }
    {   // b: bilinear dot over 256
        const float4* b4 = (const float4*)(Bq + ((size_t)b*PL + p)*256);
        float s = 0.f;
        #pragma unroll 4
        for (int e4 = 0; e4 < 64; ++e4){
            float4 v = b4[e4];
            int e = e4*4;
            s += hpr[e+0]*v.x; s += hpr[e+1]*v.y;
            s += hpr[e+2]*v.z; s += hpr[e+3]*v.w;
        }
        wbv[tid] = s;
    }
    {   // d: summed halves
        size_t si = ((size_t)b*QL + q)*PL + tid;
        wd[tid] = scd0[si] + scd1[si];
    }
    {   // s: summed halves, 128 keys
        if (tid < QL){
            size_t si = ((size_t)b*QL + q)*QL + tid;
            wsx[tid] = scs0[si] + scs1[si];
        } else {
            wsx[tid] = -1e30f;
        }
    }
    __syncthreads();

    // ---- batched 5-way softmax (wave shuffle + tiny LDS cross-wave) ----
    {
        int wid = tid >> 6, lane = tid & 63;
        float sv[5] = {wc[tid], wm[tid], wbv[tid], wd[tid], wsx[tid]};
        float mx[5], ex[5];
        #pragma unroll
        for (int i = 0; i < 5; ++i){
            float m = sv[i];
            #pragma unroll
            for (int k = 32; k >= 1; k >>= 1) m = fmaxf(m, __shfl_xor(m, k));
            mx[i] = m;
        }
        if (lane == 0){
            #pragma unroll
            for (int i = 0; i < 5; ++i) sred[0][wid][i] = mx[i];
        }
        __syncthreads();
        #pragma unroll
        for (int i = 0; i < 5; ++i){
            float m = fmaxf(fmaxf(sred[0][0][i], sred[0][1][i]),
                            fmaxf(sred[0][2][i], sred[0][3][i]));
            ex[i] = __expf(sv[i] - m);
            float s = ex[i];
            #pragma unroll
            for (int k = 32; k >= 1; k >>= 1) s += __shfl_xor(s, k);
            mx[i] = s;
        }
        if (lane == 0){
            #pragma unroll
            for (int i = 0; i < 5; ++i) sred[1][wid][i] = mx[i];
        }
        __syncthreads();
        #pragma unroll
        for (int i = 0; i < 5; ++i){
            float s = sred[1][0][i] + sred[1][1][i] + sred[1][2][i] + sred[1][3][i];
            ex[i] *= (1.f / s);
        }
        wc[tid] = ex[0]; wm[tid] = ex[1]; wbv[tid] = ex[2]; wd[tid] = ex[3]; wsx[tid] = ex[4];
        __syncthreads();
    }

    // ---- one weighted-sum pass over hq (4 outputs) ----
    float oc = 0.f, om = 0.f, ob = 0.f, od = 0.f;
    const float* hqb = hq + (size_t)b*PL*256;
    #pragma unroll 4
    for (int pp = 0; pp < PL; ++pp){
        float v = hqb[(size_t)pp*256 + tid];
        oc += wc[pp]  * v;
        om += wm[pp]  * v;
        ob += wbv[pp] * v;
        od += wd[pp]  * v;
    }
    // ---- one pass over hp (qts) ----
    float os = 0.f;
    const float* hpb = hp + (size_t)b*QL*256;
    #pragma unroll 4
    for (int k = 0; k < QL; ++k) os += wsx[k] * hpb[(size_t)k*256 + tid];

    float* ag = agg + ((size_t)b*QL + q)*1536;
    ag[ 256 + tid] = os;
    ag[ 512 + tid] = oc;
    ag[ 768 + tid] = od;
    ag[1024 + tid] = ob;
    ag[1280 + tid] = om;
}

// ---------------------------------------------------------------------------
__global__ __launch_bounds__(256) void k_p_att(const float* __restrict__ Gp,
                                               const float* __restrict__ vp,
                                               const float* __restrict__ rqW,
                                               const float* __restrict__ agg_rep,
                                               float* __restrict__ rp){
    int b = blockIdx.x, tid = threadIdx.x;
    __shared__ float vv[EE], rw[EE], sc[256], red[256];
    if (tid < EE){
        vv[tid] = vp[tid];
        rw[tid] = rqW[(size_t)b*EE + tid];
    }
    if (tid >= 128) sc[tid] = -1e30f;
    __syncthreads();
    if (tid < QL){
        const float* gp = Gp + ((size_t)b*QL + tid)*EE;
        float s = 0.f;
        for (int e = 0; e < EE; ++e) s += vv[e] * (gp[e] + rw[e]);
        sc[tid] = s;
    }
    __syncthreads();
    softmax256(sc, red, tid);
    float o = 0.f;
    const float* ab = agg_rep + (size_t)b*QL*256;
    for (int q = 0; q < QL; ++q) o += sc[q] * ab[(size_t)q*256 + tid];
    rp[(size_t)b*256 + tid] = o;
}

__global__ __launch_bounds__(256) void k_final(const float* __restrict__ rp,
                                               const float* __restrict__ Wpred,
                                               const float* __restrict__ a_emb,
                                               float* __restrict__ out){
    int b = blockIdx.x, tid = threadIdx.x;
    __shared__ float rpv[256], enc[256];
    rpv[tid] = rp[(size_t)b*256 + tid];
    __syncthreads();
    const float* wr = Wpred + (size_t)tid*256;
    float s = 0.f;
    #pragma unroll 4
    for (int e = 0; e < 256; ++e) s += wr[e] * rpv[e];
    enc[tid] = (s > 0.f) ? s : 0.01f * s;
    __syncthreads();
    if (tid < 3){
        const float* ae = a_emb + ((size_t)b*3 + tid)*256;
        float o = 0.f;
        for (int e = 0; e < 256; ++e) o += ae[e] * enc[e];
        out[b*3 + tid] = o;
    }
}

// ---------------------------------------------------------------------------
extern "C" void kernel_launch(void* const* d_in, const int* in_sizes, int n_in,
                              void* d_out, int out_size, void* d_ws, size_t ws_size,
                              hipStream_t stream){
    const float* emb   = (const float*)d_in[0];
    const float* a_att = (const float*)d_in[1];
    const float* Wc1   = (const float*)d_in[2];
    const float* Wc2   = (const float*)d_in[3];
    const float* vc    = (const float*)d_in[4];
    const float* Wb    = (const float*)d_in[5];
    const float* Wd    = (const float*)d_in[6];
    const float* vd    = (const float*)d_in[7];
    const float* Wm    = (const float*)d_in[8];
    const float* vm    = (const float*)d_in[9];
    const float* Ws    = (const float*)d_in[10];
    const float* vs    = (const float*)d_in[11];
    const float* Wq    = (const float*)d_in[12];
    const float* vq    = (const float*)d_in[13];
    const float* Wp1   = (const float*)d_in[14];
    const float* Wp2   = (const float*)d_in[15];
    const float* vp    = (const float*)d_in[16];
    const float* Wpred = (const float*)d_in[17];
    const float* q_Wih = (const float*)d_in[18];
    const float* q_Whh = (const float*)d_in[19];
    const float* q_bih = (const float*)d_in[20];
    const float* q_bhh = (const float*)d_in[21];
    const float* p_Wih = (const float*)d_in[22];
    const float* p_Whh = (const float*)d_in[23];
    const float* p_bih = (const float*)d_in[24];
    const float* p_bhh = (const float*)d_in[25];
    const float* a_Wih = (const float*)d_in[26];
    const float* a_Whh = (const float*)d_in[27];
    const float* a_bih = (const float*)d_in[28];
    const float* a_bhh = (const float*)d_in[29];
    const float* g_Wih = (const float*)d_in[30];
    const float* g_Whh = (const float*)d_in[31];
    const float* g_bih = (const float*)d_in[32];
    const float* g_bhh = (const float*)d_in[33];
    const int* query   = (const int*)d_in[34];
    const int* passage = (const int*)d_in[35];
    const int* cneg    = (const int*)d_in[36];
    const int* cpos    = (const int*)d_in[37];
    const int* cna     = (const int*)d_in[38];

    float* ws = (float*)d_ws;

    // 1. embedding gathers
    k_gather_all<<<3312, 256, 0, stream>>>(passage, query, cneg, cpos, cna, emb, ws);

    // 2. input preactivations (q | p | cand merged)
    k_pre_all<<<648, 256, 0, stream>>>(ws, q_Wih, q_bih, p_Wih, p_bih, a_Wih, a_bih);

    // 3. forward GRU scans (q || p || cand in one dispatch)
    k_gru_fwd<<<80, 512, 0, stream>>>(ws, q_Whh, q_bhh, p_Whh, p_bhh, a_Whh, a_bhh);

    // 4. projection GEMMs + cand pooling (merged)
    k_proj_all<<<408, 256, 0, stream>>>(ws, Wc1, Wc2, Wb, Wq, Wm, a_att);

    // 5. dms score halves (dot + self, merged)
    k_dms_all<<<1024, 256, 0, stream>>>(ws, Wd, vd, Ws, vs);

    // 6. fused attention -> all agg slices (+ q_att blocks)
    k_att_fused<<<1032, 256, 0, stream>>>(ws+O_AQ, ws+O_AP, vc,
                                          ws+O_MQ2, ws+O_MP2, vm,
                                          ws+O_BQ,
                                          ws+O_SCD0, ws+O_SCD1,
                                          ws+O_SCS0, ws+O_SCS1,
                                          ws+O_HQ, ws+O_HP, ws+O_AGG,
                                          ws+O_CQ, vq, ws+O_RQ);

    // 7. aggregation bigru
    k_gemm_agg<<<dim3(6,16,2), 256, 0, stream>>>(ws+O_AGG, g_Wih, g_bih, ws+O_PREG);
    k_gru_scan<<<16, 512, 0, stream>>>(ws+O_PREG, g_Whh, g_bhh, ws+O_AGGREP, 128);

    // 8. pooling + prediction
    k_fin2<<<34, 256, 0, stream>>>(ws, Wp1, Wp2);
    k_p_att<<<8, 256, 0, stream>>>(ws+O_GP, vp, ws+O_RQW, ws+O_AGGREP, ws+O_RP);
    k_final<<<8, 256, 0, stream>>>(ws+O_RP, Wpred, ws+O_AEMB, (float*)d_out);
}